// Round 5
// baseline (465.354 us; speedup 1.0000x reference)
//
#include <hip/hip_runtime.h>

#define HDIM 256
#define MDIM 64
#define GNUM 128

typedef short bf16x8 __attribute__((ext_vector_type(8)));
typedef float f32x4 __attribute__((ext_vector_type(4)));
typedef unsigned short u16;
typedef unsigned int u32;

__device__ __forceinline__ u32 f2bf(float f) {
  u32 u = __float_as_uint(f);
  return (u + 0x7FFFu + ((u >> 16) & 1u)) >> 16;   // RNE
}
__device__ __forceinline__ float bf2f(u16 h) {
  return __uint_as_float((u32)h << 16);
}
__device__ __forceinline__ u32 pack2(float a, float b) {
  return f2bf(a) | (f2bf(b) << 16);
}

// ============ weight prep: fragment-major hi/lo layouts ============
// W1F record rec = c*32 + ks*16 + w*4 + ht  (c:12, ks:2, w:4, ht:4) -> 384 recs
//   lane l=(q*16+r): 8 bf16 = W1[kg0..kg0+7][hcol], kg0=(c%3)*256+(c/3)*64+ks*32+q*8,
//   hcol = w*64+ht*16+r.  offset u16 = (rec*64+l)*8.
// W2F record rec2 = ks2*4 + nt (32 recs): lane l: W2[k0..k0+7][m], k0=ks2*32+q*8, m=nt*16+r.
__global__ __launch_bounds__(256) void prep_k(const float* __restrict__ W1,
                                              const float* __restrict__ W2,
                                              u16* __restrict__ W1Fh, u16* __restrict__ W1Fl,
                                              u16* __restrict__ W2Fh, u16* __restrict__ W2Fl) {
  int tid = blockIdx.x * 256 + threadIdx.x;
  if (tid < 24576) {
    int rec = tid >> 6, l = tid & 63;
    int c = rec >> 5, rem = rec & 31;
    int ks = rem >> 4, w = (rem >> 2) & 3, ht = rem & 3;
    int q = l >> 4, r = l & 15;
    int hcol = w * 64 + ht * 16 + r;
    int kg0 = (c % 3) * 256 + (c / 3) * 64 + ks * 32 + q * 8;
    u16 hv[8], lv[8];
    #pragma unroll
    for (int i = 0; i < 8; ++i) {
      float f = W1[(size_t)(kg0 + i) * HDIM + hcol];
      u16 h = (u16)f2bf(f);
      hv[i] = h;
      lv[i] = (u16)f2bf(f - bf2f(h));
    }
    #pragma unroll
    for (int i = 0; i < 8; ++i) { W1Fh[tid * 8 + i] = hv[i]; W1Fl[tid * 8 + i] = lv[i]; }
  } else if (tid < 24576 + 2048) {
    int t2 = tid - 24576;
    int rec = t2 >> 6, l = t2 & 63;
    int ks2 = rec >> 2, nt = rec & 3;
    int q = l >> 4, r = l & 15;
    int m = nt * 16 + r;
    int k0 = ks2 * 32 + q * 8;
    u16 hv[8], lv[8];
    #pragma unroll
    for (int i = 0; i < 8; ++i) {
      float f = W2[(size_t)(k0 + i) * MDIM + m];
      u16 h = (u16)f2bf(f);
      hv[i] = h;
      lv[i] = (u16)f2bf(f - bf2f(h));
    }
    #pragma unroll
    for (int i = 0; i < 8; ++i) { W2Fh[t2 * 8 + i] = hv[i]; W2Fl[t2 * 8 + i] = lv[i]; }
  }
}

// ============ CSR build: count ============
__global__ __launch_bounds__(256) void count_k(const int* __restrict__ ei,
                                               int* __restrict__ degInt, int E) {
  int e = blockIdx.x * 256 + threadIdx.x;
  if (e >= E) return;
  atomicAdd(&degInt[ei[e]], 1);
}

// ============ scan level 1 ============
__global__ __launch_bounds__(256) void scan1_k(const int* __restrict__ degInt,
                                               int* __restrict__ nodeOff,
                                               int* __restrict__ blkSum, int N) {
  __shared__ int sdata[256];
  int b = blockIdx.x, t = threadIdx.x;
  int base = b * 1024 + t * 4;
  int v[4];
  #pragma unroll
  for (int q = 0; q < 4; ++q) v[q] = (base + q < N) ? degInt[base + q] : 0;
  int tsum = v[0] + v[1] + v[2] + v[3];
  sdata[t] = tsum;
  __syncthreads();
  for (int off = 1; off < 256; off <<= 1) {
    int xv = (t >= off) ? sdata[t - off] : 0;
    __syncthreads();
    sdata[t] += xv;
    __syncthreads();
  }
  int run = sdata[t] - tsum;
  #pragma unroll
  for (int q = 0; q < 4; ++q) {
    if (base + q < N) nodeOff[base + q] = run;
    run += v[q];
  }
  if (t == 255) blkSum[b] = sdata[255];
}

// ============ scan level 2 ============
__global__ __launch_bounds__(128) void scan2_k(const int* __restrict__ blkSum,
                                               int* __restrict__ blkOff, int NB) {
  __shared__ int sdata[128];
  int t = threadIdx.x;
  int v = (t < NB) ? blkSum[t] : 0;
  sdata[t] = v;
  __syncthreads();
  for (int off = 1; off < 128; off <<= 1) {
    int xv = (t >= off) ? sdata[t - off] : 0;
    __syncthreads();
    sdata[t] += xv;
    __syncthreads();
  }
  if (t < NB) blkOff[t] = sdata[t] - v;
}

// ============ scan level 3 ============
__global__ __launch_bounds__(256) void scan3_k(int* __restrict__ nodeOff,
                                               const int* __restrict__ blkOff,
                                               int* __restrict__ cursor, int N) {
  int i = blockIdx.x * 256 + threadIdx.x;
  if (i >= N) return;
  int off = nodeOff[i] + blkOff[i >> 10];
  nodeOff[i] = off;
  cursor[i] = off;
}

// ============ CSR fill ============
__global__ __launch_bounds__(256) void fill_k(const int* __restrict__ ei,
                                              int* __restrict__ cursor,
                                              int* __restrict__ csrDst, int E) {
  int e = blockIdx.x * 256 + threadIdx.x;
  if (e >= E) return;
  int p = atomicAdd(&cursor[ei[e]], 1);
  csrDst[p] = ei[E + e];
}

// ============ aggregation gather: one wave per node, 4 gathers in flight ============
__global__ __launch_bounds__(256) void agg_k(const float* __restrict__ x,
                                             const int* __restrict__ nodeOff,
                                             const int* __restrict__ degInt,
                                             const int* __restrict__ csrDst,
                                             float* __restrict__ agg, int N) {
  int wave = blockIdx.x * 4 + (threadIdx.x >> 6);
  int lane = threadIdx.x & 63;
  if (wave >= N) return;
  int deg = degInt[wave];
  int start = nodeOff[wave];
  float4 acc = make_float4(0.f, 0.f, 0.f, 0.f);
  int j = 0;
  for (; j + 4 <= deg; j += 4) {
    int d0 = csrDst[start + j + 0];
    int d1 = csrDst[start + j + 1];
    int d2 = csrDst[start + j + 2];
    int d3 = csrDst[start + j + 3];
    float4 v0 = reinterpret_cast<const float4*>(x + (size_t)d0 * HDIM)[lane];
    float4 v1 = reinterpret_cast<const float4*>(x + (size_t)d1 * HDIM)[lane];
    float4 v2 = reinterpret_cast<const float4*>(x + (size_t)d2 * HDIM)[lane];
    float4 v3 = reinterpret_cast<const float4*>(x + (size_t)d3 * HDIM)[lane];
    acc.x += (v0.x + v1.x) + (v2.x + v3.x);
    acc.y += (v0.y + v1.y) + (v2.y + v3.y);
    acc.z += (v0.z + v1.z) + (v2.z + v3.z);
    acc.w += (v0.w + v1.w) + (v2.w + v3.w);
  }
  for (; j < deg; ++j) {
    int d = csrDst[start + j];
    float4 v = reinterpret_cast<const float4*>(x + (size_t)d * HDIM)[lane];
    acc.x += v.x; acc.y += v.y; acc.z += v.z; acc.w += v.w;
  }
  float s = deg > 0 ? 1.0f / (float)deg : 0.0f;
  acc.x *= s; acc.y *= s; acc.z *= s; acc.w *= s;
  reinterpret_cast<float4*>(agg + (size_t)wave * HDIM)[lane] = acc;
}

// ============ fused MFMA MLP + pool (W frags direct global->reg) ============
// 64 nodes/block, 4 waves; wave w owns h-cols [64w,64w+64).
// A tile (feat bf16, XOR-swz) double-buffered 2x8KB; ONE barrier per chunk.
// Chunk c: qk=c/3, seg=c%3 (x | agg | x*agg); x/agg quarters loaded once.
__global__ __launch_bounds__(256, 2) void fused_mfma_k(
    const float* __restrict__ x, const float* __restrict__ agg,
    const int* __restrict__ batch,
    const u16* __restrict__ W1Fh, const u16* __restrict__ W1Fl,
    const float* __restrict__ b1,
    const u16* __restrict__ W2Fh, const u16* __restrict__ W2Fl,
    const float* __restrict__ b2,
    float* __restrict__ sums, int N) {
  __shared__ __align__(16) char smem[32768];   // A dbuf 2x8KB; later Hs 32KB

  const int t = threadIdx.x;
  const int w = t >> 6;
  const int l = t & 63;
  const int r15 = l & 15;
  const int q = l >> 4;
  const int rx = r15 & 7;
  const int n0 = blockIdx.x * 64;

  f32x4 acc[4][4];
  #pragma unroll
  for (int i = 0; i < 4; ++i)
    #pragma unroll
    for (int j = 0; j < 4; ++j) acc[i][j] = (f32x4){0.f, 0.f, 0.f, 0.f};

  float4 X[4], A[4], Xn[4], An[4];

#define LOADQ(srcp, qk, dst)                                                   \
  {                                                                            \
    _Pragma("unroll")                                                          \
    for (int p = 0; p < 4; ++p) {                                              \
      int g = t + 256 * p, nd = g >> 4, kq = g & 15;                           \
      int node = n0 + nd;                                                      \
      dst[p] = (node < N)                                                      \
          ? *(const float4*)(srcp + (size_t)node * HDIM + (qk) * 64 + kq * 4)  \
          : make_float4(0.f, 0.f, 0.f, 0.f);                                   \
    }                                                                          \
  }
#define WRITEA(bufi, v0, v1, v2, v3)                                           \
  {                                                                            \
    float4 vv[4] = {v0, v1, v2, v3};                                           \
    _Pragma("unroll")                                                          \
    for (int p = 0; p < 4; ++p) {                                              \
      int g = t + 256 * p, nd = g >> 4, kq = g & 15;                           \
      int byte = (bufi) * 8192 + ((nd * 128 + kq * 8) ^ ((nd & 7) << 4));      \
      *(uint2*)(smem + byte) =                                                 \
          make_uint2(pack2(vv[p].x, vv[p].y), pack2(vv[p].z, vv[p].w));        \
    }                                                                          \
  }

  // prologue: A[0] = x quarter 0; issue agg[0] for A[1]
  LOADQ(x, 0, X);
  WRITEA(0, X[0], X[1], X[2], X[3]);
  LOADQ(agg, 0, An);

  #pragma unroll
  for (int c = 0; c < 12; ++c) {
    __syncthreads();   // A[c] visible; reads of buf[(c+1)&1] (chunk c-1) done
    // ---- write A[c+1] into buf[(c+1)&1] ----
    const int c1 = c + 1;
    if (c1 < 12) {
      const int s1 = c1 % 3;
      if (s1 == 0) {
        WRITEA(c1 & 1, Xn[0], Xn[1], Xn[2], Xn[3]);
        #pragma unroll
        for (int p = 0; p < 4; ++p) X[p] = Xn[p];
      } else if (s1 == 1) {
        WRITEA(c1 & 1, An[0], An[1], An[2], An[3]);
        #pragma unroll
        for (int p = 0; p < 4; ++p) A[p] = An[p];
      } else {
        float4 pr[4];
        #pragma unroll
        for (int p = 0; p < 4; ++p)
          pr[p] = make_float4(X[p].x * A[p].x, X[p].y * A[p].y,
                              X[p].z * A[p].z, X[p].w * A[p].w);
        WRITEA(c1 & 1, pr[0], pr[1], pr[2], pr[3]);
      }
    }
    // ---- issue global loads for chunk c+2's write ----
    const int c2 = c + 2;
    if (c2 < 12) {
      if (c2 % 3 == 0) { LOADQ(x, c2 / 3, Xn); }
      else if (c2 % 3 == 1) { LOADQ(agg, c2 / 3, An); }
    }
    // ---- MFMA chunk c from buf[c&1]; W frags straight from global ----
    #pragma unroll
    for (int ks = 0; ks < 2; ++ks) {
      bf16x8 bfr[4];
      #pragma unroll
      for (int nt = 0; nt < 4; ++nt)
        bfr[nt] = *(const bf16x8*)(smem + (c & 1) * 8192 +
                                   (nt * 16 + r15) * 128 + (((ks * 4 + q) ^ rx) << 4));
      const int recb = c * 32 + ks * 16 + w * 4;
      #pragma unroll
      for (int ht = 0; ht < 4; ++ht) {
        bf16x8 ah = *(const bf16x8*)(W1Fh + (size_t)(recb + ht) * 512 + l * 8);
        bf16x8 al = *(const bf16x8*)(W1Fl + (size_t)(recb + ht) * 512 + l * 8);
        #pragma unroll
        for (int nt = 0; nt < 4; ++nt)
          acc[ht][nt] = __builtin_amdgcn_mfma_f32_16x16x32_bf16(ah, bfr[nt],
                                                                acc[ht][nt], 0, 0, 0);
        #pragma unroll
        for (int nt = 0; nt < 4; ++nt)
          acc[ht][nt] = __builtin_amdgcn_mfma_f32_16x16x32_bf16(al, bfr[nt],
                                                                acc[ht][nt], 0, 0, 0);
      }
    }
  }

  // ---- h = relu(acc + b1) -> Hs bf16 (smem reused) ----
  __syncthreads();
  #pragma unroll
  for (int mt = 0; mt < 4; ++mt) {
    float4 b1v = *(const float4*)(b1 + w * 64 + mt * 16 + q * 4);
    #pragma unroll
    for (int nt = 0; nt < 4; ++nt) {
      f32x4 a = acc[mt][nt];
      float h0 = fmaxf(a[0] + b1v.x, 0.f);
      float h1 = fmaxf(a[1] + b1v.y, 0.f);
      float h2 = fmaxf(a[2] + b1v.z, 0.f);
      float h3 = fmaxf(a[3] + b1v.w, 0.f);
      int node = nt * 16 + r15;
      int hcol = w * 64 + mt * 16 + q * 4;
      int byte = (node * 512 + hcol * 2) ^ ((r15 & 7) << 4);
      *(uint2*)(smem + byte) = make_uint2(pack2(h0, h1), pack2(h2, h3));
    }
  }
  __syncthreads();

  // ---- GEMM2: wave w -> nodes [16w,16w+16); W2 frags from global ----
  f32x4 acc2[4];
  #pragma unroll
  for (int nt = 0; nt < 4; ++nt) acc2[nt] = (f32x4){0.f, 0.f, 0.f, 0.f};
  #pragma unroll
  for (int ks2 = 0; ks2 < 8; ++ks2) {
    int hb = ((w * 16 + r15) * 512 + ks2 * 64 + q * 16) ^ ((r15 & 7) << 4);
    bf16x8 ah = *(const bf16x8*)(smem + hb);
    #pragma unroll
    for (int nt = 0; nt < 4; ++nt) {
      int rec2 = ks2 * 4 + nt;
      bf16x8 wbh = *(const bf16x8*)(W2Fh + rec2 * 512 + l * 8);
      bf16x8 wbl = *(const bf16x8*)(W2Fl + rec2 * 512 + l * 8);
      acc2[nt] = __builtin_amdgcn_mfma_f32_16x16x32_bf16(ah, wbh, acc2[nt], 0, 0, 0);
      acc2[nt] = __builtin_amdgcn_mfma_f32_16x16x32_bf16(ah, wbl, acc2[nt], 0, 0, 0);
    }
  }

  // ---- pool: lane (r15,q) holds emb[node = 16w+4q+reg][m = nt*16+r15] ----
  float b2v[4];
  #pragma unroll
  for (int nt = 0; nt < 4; ++nt) b2v[nt] = b2[nt * 16 + r15];

  int stripbase = n0 + w * 16;
  int guni = -1;
  if (stripbase + 15 < N) {
    int gf = batch[stripbase], gl = batch[stripbase + 15];
    if (gf == gl) guni = gf;
  }
  if (guni >= 0) {
    #pragma unroll
    for (int nt = 0; nt < 4; ++nt) {
      float s = acc2[nt][0] + acc2[nt][1] + acc2[nt][2] + acc2[nt][3] + 4.0f * b2v[nt];
      s += __shfl_xor(s, 16, 64);
      s += __shfl_xor(s, 32, 64);
      if (q == 0)
        unsafeAtomicAdd(&sums[(size_t)guni * MDIM + nt * 16 + r15], s);
    }
  } else {
    int nb = stripbase + q * 4;
    int gv[4];
    #pragma unroll
    for (int r = 0; r < 4; ++r) gv[r] = (nb + r < N) ? batch[nb + r] : -1;
    #pragma unroll
    for (int nt = 0; nt < 4; ++nt) {
      float run = 0.f;
      #pragma unroll
      for (int r = 0; r < 4; ++r) {
        bool valid = gv[r] >= 0;
        run += valid ? (acc2[nt][r] + b2v[nt]) : 0.f;
        bool endrun = valid && ((r == 3) ? true : (gv[r + 1] != gv[r]));
        if (endrun) {
          unsafeAtomicAdd(&sums[(size_t)gv[r] * MDIM + nt * 16 + r15], run);
          run = 0.f;
        }
      }
    }
  }
#undef LOADQ
#undef WRITEA
}

// ============ final: out = sums / counts ============
__global__ __launch_bounds__(256) void final_div_k(const float* __restrict__ sums,
                                                   const int* __restrict__ batch,
                                                   float* __restrict__ out, int N) {
  int i = blockIdx.x * 256 + threadIdx.x;
  if (i >= GNUM * MDIM) return;
  int g = i >> 6;
  int lo = 0, hi = N;
  while (lo < hi) { int mid = (lo + hi) >> 1; if (batch[mid] < g) lo = mid + 1; else hi = mid; }
  int lb = lo;
  lo = 0; hi = N;
  while (lo < hi) { int mid = (lo + hi) >> 1; if (batch[mid] < g + 1) lo = mid + 1; else hi = mid; }
  float cnt = (float)(lo - lb);
  out[i] = sums[i] / fmaxf(cnt, 1.0f);
}

extern "C" void kernel_launch(void* const* d_in, const int* in_sizes, int n_in,
                              void* d_out, int out_size, void* d_ws, size_t ws_size,
                              hipStream_t stream) {
  const float* x   = (const float*)d_in[0];
  const int* ei    = (const int*)d_in[1];
  const int* batch = (const int*)d_in[2];
  const float* W1  = (const float*)d_in[3];
  const float* b1  = (const float*)d_in[4];
  const float* W2  = (const float*)d_in[5];
  const float* b2  = (const float*)d_in[6];
  float* out = (float*)d_out;

  const int N = in_sizes[0] / HDIM;   // 100000
  const int E = in_sizes[1] / 2;      // 400000
  const int NB = (N + 1023) / 1024;

  int* degInt   = (int*)d_ws;                       // N
  float* sums   = (float*)(degInt + N);             // GNUM*MDIM
  float* agg    = sums + GNUM * MDIM;               // N*HDIM
  int* nodeOff  = (int*)(agg + (size_t)N * HDIM);   // N
  int* cursor   = nodeOff + N;                      // N
  int* blkSum   = cursor + N;                       // 128
  int* blkOff   = blkSum + 128;                     // 128
  int* csrDst   = blkOff + 128;                     // E
  u16* W1Fh     = (u16*)(csrDst + E);               // 384*512 = 196608
  u16* W1Fl     = W1Fh + 196608;
  u16* W2Fh     = W1Fl + 196608;                    // 32*512 = 16384
  u16* W2Fl     = W2Fh + 16384;

  hipMemsetAsync(d_ws, 0, (size_t)(N + GNUM * MDIM) * sizeof(int), stream);

  prep_k<<<104, 256, 0, stream>>>(W1, W2, W1Fh, W1Fl, W2Fh, W2Fl);
  count_k<<<(E + 255) / 256, 256, 0, stream>>>(ei, degInt, E);
  scan1_k<<<NB, 256, 0, stream>>>(degInt, nodeOff, blkSum, N);
  scan2_k<<<1, 128, 0, stream>>>(blkSum, blkOff, NB);
  scan3_k<<<(N + 255) / 256, 256, 0, stream>>>(nodeOff, blkOff, cursor, N);
  fill_k<<<(E + 255) / 256, 256, 0, stream>>>(ei, cursor, csrDst, E);
  agg_k<<<(N + 3) / 4, 256, 0, stream>>>(x, nodeOff, degInt, csrDst, agg, N);
  fused_mfma_k<<<(N + 63) / 64, 256, 0, stream>>>(x, agg, batch, W1Fh, W1Fl, b1,
                                                  W2Fh, W2Fl, b2, sums, N);
  final_div_k<<<(GNUM * MDIM + 255) / 256, 256, 0, stream>>>(sums, batch, out, N);
}

// Round 7
// 419.924 us; speedup vs baseline: 1.1082x; 1.1082x over previous
//
#include <hip/hip_runtime.h>

#define HDIM 256
#define MDIM 64
#define GNUM 128

typedef short bf16x8 __attribute__((ext_vector_type(8)));
typedef float f32x4 __attribute__((ext_vector_type(4)));
typedef unsigned short u16;
typedef unsigned int u32;

__device__ __forceinline__ u32 f2bf(float f) {
  u32 u = __float_as_uint(f);
  return (u + 0x7FFFu + ((u >> 16) & 1u)) >> 16;   // RNE
}
__device__ __forceinline__ float bf2f(u16 h) {
  return __uint_as_float((u32)h << 16);
}
__device__ __forceinline__ u32 pack2(float a, float b) {
  return f2bf(a) | (f2bf(b) << 16);
}
__device__ __forceinline__ bf16x8 bfmul8(bf16x8 a, bf16x8 b) {
  bf16x8 r;
  #pragma unroll
  for (int i = 0; i < 8; i += 2) {
    float x0 = bf2f((u16)a[i]),     y0 = bf2f((u16)b[i]);
    float x1 = bf2f((u16)a[i + 1]), y1 = bf2f((u16)b[i + 1]);
    u32 p = pack2(x0 * y0, x1 * y1);
    r[i] = (short)(p & 0xffff);
    r[i + 1] = (short)(p >> 16);
  }
  return r;
}

// ============ x f32 -> bf16 ============
__global__ __launch_bounds__(256) void cvt_k(const float* __restrict__ x,
                                             u16* __restrict__ x_bf, int n8) {
  int i = blockIdx.x * 256 + threadIdx.x;
  if (i >= n8) return;
  const float4* p = (const float4*)x + (size_t)i * 2;
  float4 a = p[0], b = p[1];
  uint4 o = make_uint4(pack2(a.x, a.y), pack2(a.z, a.w),
                       pack2(b.x, b.y), pack2(b.z, b.w));
  ((uint4*)x_bf)[i] = o;
}

// ============ weight prep: fragment-major hi/lo layouts ============
// W1F rec = c*32 + ks*16 + w*4 + ht; lane l=(q*16+r): 8 bf16 = W1[kg0..+7][hcol],
//   kg0=(c%3)*256+(c/3)*64+ks*32+q*8, hcol=w*64+ht*16+r.
// W2F rec2 = ks2*4+nt: lane l: W2[k0..+7][m], k0=ks2*32+q*8, m=nt*16+r.
__global__ __launch_bounds__(256) void prep_k(const float* __restrict__ W1,
                                              const float* __restrict__ W2,
                                              u16* __restrict__ W1Fh, u16* __restrict__ W1Fl,
                                              u16* __restrict__ W2Fh, u16* __restrict__ W2Fl) {
  int tid = blockIdx.x * 256 + threadIdx.x;
  if (tid < 24576) {
    int rec = tid >> 6, l = tid & 63;
    int c = rec >> 5, rem = rec & 31;
    int ks = rem >> 4, w = (rem >> 2) & 3, ht = rem & 3;
    int q = l >> 4, r = l & 15;
    int hcol = w * 64 + ht * 16 + r;
    int kg0 = (c % 3) * 256 + (c / 3) * 64 + ks * 32 + q * 8;
    #pragma unroll
    for (int i = 0; i < 8; ++i) {
      float f = W1[(size_t)(kg0 + i) * HDIM + hcol];
      u16 h = (u16)f2bf(f);
      W1Fh[tid * 8 + i] = h;
      W1Fl[tid * 8 + i] = (u16)f2bf(f - bf2f(h));
    }
  } else if (tid < 24576 + 2048) {
    int t2 = tid - 24576;
    int rec = t2 >> 6, l = t2 & 63;
    int ks2 = rec >> 2, nt = rec & 3;
    int q = l >> 4, r = l & 15;
    int m = nt * 16 + r;
    int k0 = ks2 * 32 + q * 8;
    #pragma unroll
    for (int i = 0; i < 8; ++i) {
      float f = W2[(size_t)(k0 + i) * MDIM + m];
      u16 h = (u16)f2bf(f);
      W2Fh[t2 * 8 + i] = h;
      W2Fl[t2 * 8 + i] = (u16)f2bf(f - bf2f(h));
    }
  }
}

// ============ CSR build ============
__global__ __launch_bounds__(256) void count_k(const int* __restrict__ ei,
                                               int* __restrict__ degInt, int E) {
  int e = blockIdx.x * 256 + threadIdx.x;
  if (e >= E) return;
  atomicAdd(&degInt[ei[e]], 1);
}

__global__ __launch_bounds__(256) void scan1_k(const int* __restrict__ degInt,
                                               int* __restrict__ nodeOff,
                                               int* __restrict__ blkSum, int N) {
  __shared__ int sdata[256];
  int b = blockIdx.x, t = threadIdx.x;
  int base = b * 1024 + t * 4;
  int v[4];
  #pragma unroll
  for (int q = 0; q < 4; ++q) v[q] = (base + q < N) ? degInt[base + q] : 0;
  int tsum = v[0] + v[1] + v[2] + v[3];
  sdata[t] = tsum;
  __syncthreads();
  for (int off = 1; off < 256; off <<= 1) {
    int xv = (t >= off) ? sdata[t - off] : 0;
    __syncthreads();
    sdata[t] += xv;
    __syncthreads();
  }
  int run = sdata[t] - tsum;
  #pragma unroll
  for (int q = 0; q < 4; ++q) {
    if (base + q < N) nodeOff[base + q] = run;
    run += v[q];
  }
  if (t == 255) blkSum[b] = sdata[255];
}

__global__ __launch_bounds__(128) void scan2_k(const int* __restrict__ blkSum,
                                               int* __restrict__ blkOff, int NB) {
  __shared__ int sdata[128];
  int t = threadIdx.x;
  int v = (t < NB) ? blkSum[t] : 0;
  sdata[t] = v;
  __syncthreads();
  for (int off = 1; off < 128; off <<= 1) {
    int xv = (t >= off) ? sdata[t - off] : 0;
    __syncthreads();
    sdata[t] += xv;
    __syncthreads();
  }
  if (t < NB) blkOff[t] = sdata[t] - v;
}

__global__ __launch_bounds__(256) void scan3_k(int* __restrict__ nodeOff,
                                               const int* __restrict__ blkOff,
                                               int* __restrict__ cursor, int N) {
  int i = blockIdx.x * 256 + threadIdx.x;
  if (i >= N) return;
  int off = nodeOff[i] + blkOff[i >> 10];
  nodeOff[i] = off;
  cursor[i] = off;
}

__global__ __launch_bounds__(256) void fill_k(const int* __restrict__ ei,
                                              int* __restrict__ cursor,
                                              int* __restrict__ csrDst, int E) {
  int e = blockIdx.x * 256 + threadIdx.x;
  if (e >= E) return;
  int p = atomicAdd(&cursor[ei[e]], 1);
  csrDst[p] = ei[E + e];
}

// ============ aggregation gather (bf16 rows, 512 B each) ============
__global__ __launch_bounds__(256) void agg_k(const u16* __restrict__ x_bf,
                                             const int* __restrict__ nodeOff,
                                             const int* __restrict__ degInt,
                                             const int* __restrict__ csrDst,
                                             u16* __restrict__ agg_bf, int N) {
  int wave = blockIdx.x * 4 + (threadIdx.x >> 6);
  int lane = threadIdx.x & 63;
  if (wave >= N) return;
  int deg = degInt[wave];
  int start = nodeOff[wave];
  const char* xB = (const char*)x_bf;
  float a0 = 0.f, a1 = 0.f, a2 = 0.f, a3 = 0.f;
#define ADDV(v)                              \
  a0 += bf2f((u16)((v).x & 0xffff));         \
  a1 += bf2f((u16)((v).x >> 16));            \
  a2 += bf2f((u16)((v).y & 0xffff));         \
  a3 += bf2f((u16)((v).y >> 16));
  int j = 0;
  for (; j + 4 <= deg; j += 4) {
    int d0 = csrDst[start + j + 0];
    int d1 = csrDst[start + j + 1];
    int d2 = csrDst[start + j + 2];
    int d3 = csrDst[start + j + 3];
    uint2 v0 = *(const uint2*)(xB + (size_t)d0 * 512 + lane * 8);
    uint2 v1 = *(const uint2*)(xB + (size_t)d1 * 512 + lane * 8);
    uint2 v2 = *(const uint2*)(xB + (size_t)d2 * 512 + lane * 8);
    uint2 v3 = *(const uint2*)(xB + (size_t)d3 * 512 + lane * 8);
    ADDV(v0) ADDV(v1) ADDV(v2) ADDV(v3)
  }
  for (; j < deg; ++j) {
    int d = csrDst[start + j];
    uint2 v = *(const uint2*)(xB + (size_t)d * 512 + lane * 8);
    ADDV(v)
  }
#undef ADDV
  float s = deg > 0 ? 1.0f / (float)deg : 0.0f;
  a0 *= s; a1 *= s; a2 *= s; a3 *= s;
  *(uint2*)((char*)agg_bf + (size_t)wave * 512 + lane * 8) =
      make_uint2(pack2(a0, a1), pack2(a2, a3));
}

// ============ fused MFMA MLP + pool: barrier-free GEMM1, reg-pipelined ============
// 64 nodes/block, 4 waves; wave w owns h-cols [64w,64w+64).
// Step s = c*2+ks (24 steps). A-frags direct from x_bf/agg_bf (L1); W-frags
// from W1F (L2), both prefetched one step ahead in named ping-pong reg sets.
__global__ __launch_bounds__(256, 2) void fused_mfma_k(
    const u16* __restrict__ x_bf, const u16* __restrict__ agg_bf,
    const int* __restrict__ batch,
    const u16* __restrict__ W1Fh, const u16* __restrict__ W1Fl,
    const float* __restrict__ b1,
    const u16* __restrict__ W2Fh, const u16* __restrict__ W2Fl,
    const float* __restrict__ b2,
    float* __restrict__ sums, int N) {
  __shared__ __align__(16) char smem[32768];   // Hs only

  const int t = threadIdx.x;
  const int w = t >> 6;
  const int l = t & 63;
  const int r15 = l & 15;
  const int q = l >> 4;
  const int n0 = blockIdx.x * 64;

  const char* xB = (const char*)x_bf;
  const char* aB = (const char*)agg_bf;
  const size_t arow = (size_t)(n0 + r15) * 512 + q * 16;

  f32x4 acc[4][4];
  #pragma unroll
  for (int i = 0; i < 4; ++i)
    #pragma unroll
    for (int j = 0; j < 4; ++j) acc[i][j] = (f32x4){0.f, 0.f, 0.f, 0.f};

  bf16x8 W0h[4], W0l[4], W1h_[4], W1l_[4];
  bf16x8 A0x[4], A0a[4], A1x[4], A1a[4];

#define LOADW(s, WH, WL)                                                        \
  {                                                                             \
    _Pragma("unroll")                                                           \
    for (int ht = 0; ht < 4; ++ht) {                                            \
      size_t off = (size_t)(s)*16384 + (size_t)w * 4096 + (size_t)ht * 1024 +   \
                   (size_t)l * 16;                                              \
      WH[ht] = *(const bf16x8*)((const char*)W1Fh + off);                       \
      WL[ht] = *(const bf16x8*)((const char*)W1Fl + off);                       \
    }                                                                           \
  }
#define LOADA(s, AX, AA)                                                        \
  {                                                                             \
    const int c_ = (s) >> 1, seg_ = c_ % 3, qk_ = c_ / 3, ks_ = (s)&1;          \
    _Pragma("unroll")                                                           \
    for (int nt = 0; nt < 4; ++nt) {                                            \
      size_t off = arow + (size_t)nt * 8192 + (size_t)qk_ * 128 + ks_ * 64;     \
      if (seg_ == 0) AX[nt] = *(const bf16x8*)(xB + off);                       \
      else if (seg_ == 1) AX[nt] = *(const bf16x8*)(aB + off);                  \
      else {                                                                    \
        AX[nt] = *(const bf16x8*)(xB + off);                                    \
        AA[nt] = *(const bf16x8*)(aB + off);                                    \
      }                                                                         \
    }                                                                           \
  }
#define CONS(s, WH, WL, AX, AA)                                                 \
  {                                                                             \
    const int seg_ = ((s) >> 1) % 3;                                            \
    bf16x8 bfr[4];                                                              \
    _Pragma("unroll")                                                           \
    for (int nt = 0; nt < 4; ++nt)                                              \
      bfr[nt] = (seg_ < 2) ? AX[nt] : bfmul8(AX[nt], AA[nt]);                   \
    __builtin_amdgcn_s_setprio(1);                                              \
    _Pragma("unroll")                                                           \
    for (int ht = 0; ht < 4; ++ht) {                                            \
      _Pragma("unroll")                                                         \
      for (int nt = 0; nt < 4; ++nt)                                            \
        acc[ht][nt] = __builtin_amdgcn_mfma_f32_16x16x32_bf16(WH[ht], bfr[nt],  \
                                                              acc[ht][nt], 0, 0, 0); \
      _Pragma("unroll")                                                         \
      for (int nt = 0; nt < 4; ++nt)                                            \
        acc[ht][nt] = __builtin_amdgcn_mfma_f32_16x16x32_bf16(WL[ht], bfr[nt],  \
                                                              acc[ht][nt], 0, 0, 0); \
    }                                                                           \
    __builtin_amdgcn_s_setprio(0);                                              \
  }

  LOADW(0, W0h, W0l)
  LOADA(0, A0x, A0a)
  #pragma unroll
  for (int c = 0; c < 12; ++c) {
    const int s0 = 2 * c;
    LOADW(s0 + 1, W1h_, W1l_)
    LOADA(s0 + 1, A1x, A1a)
    CONS(s0, W0h, W0l, A0x, A0a)
    if (c < 11) {
      LOADW(s0 + 2, W0h, W0l)
      LOADA(s0 + 2, A0x, A0a)
    }
    CONS(s0 + 1, W1h_, W1l_, A1x, A1a)
  }
#undef LOADW
#undef LOADA
#undef CONS

  // ---- h = relu(acc + b1) -> Hs bf16 ----
  #pragma unroll
  for (int mt = 0; mt < 4; ++mt) {
    float4 b1v = *(const float4*)(b1 + w * 64 + mt * 16 + q * 4);
    #pragma unroll
    for (int nt = 0; nt < 4; ++nt) {
      f32x4 a = acc[mt][nt];
      float h0 = fmaxf(a[0] + b1v.x, 0.f);
      float h1 = fmaxf(a[1] + b1v.y, 0.f);
      float h2 = fmaxf(a[2] + b1v.z, 0.f);
      float h3 = fmaxf(a[3] + b1v.w, 0.f);
      int node = nt * 16 + r15;
      int hcol = w * 64 + mt * 16 + q * 4;
      int byte = (node * 512 + hcol * 2) ^ ((r15 & 7) << 4);
      *(uint2*)(smem + byte) = make_uint2(pack2(h0, h1), pack2(h2, h3));
    }
  }
  __syncthreads();

  // ---- GEMM2: wave w -> nodes [16w,16w+16); W2 frags from global ----
  f32x4 acc2[4];
  #pragma unroll
  for (int nt = 0; nt < 4; ++nt) acc2[nt] = (f32x4){0.f, 0.f, 0.f, 0.f};
  #pragma unroll
  for (int ks2 = 0; ks2 < 8; ++ks2) {
    int hb = ((w * 16 + r15) * 512 + ks2 * 64 + q * 16) ^ ((r15 & 7) << 4);
    bf16x8 ah = *(const bf16x8*)(smem + hb);
    #pragma unroll
    for (int nt = 0; nt < 4; ++nt) {
      int rec2 = ks2 * 4 + nt;
      bf16x8 wbh = *(const bf16x8*)(W2Fh + rec2 * 512 + l * 8);
      bf16x8 wbl = *(const bf16x8*)(W2Fl + rec2 * 512 + l * 8);
      acc2[nt] = __builtin_amdgcn_mfma_f32_16x16x32_bf16(ah, wbh, acc2[nt], 0, 0, 0);
      acc2[nt] = __builtin_amdgcn_mfma_f32_16x16x32_bf16(ah, wbl, acc2[nt], 0, 0, 0);
    }
  }

  // ---- pool: lane (r15,q) holds emb[node = 16w+4q+reg][m = nt*16+r15] ----
  float b2v[4];
  #pragma unroll
  for (int nt = 0; nt < 4; ++nt) b2v[nt] = b2[nt * 16 + r15];

  int stripbase = n0 + w * 16;
  int guni = -1;
  if (stripbase + 15 < N) {
    int gf = batch[stripbase], gl = batch[stripbase + 15];
    if (gf == gl) guni = gf;
  }
  if (guni >= 0) {
    #pragma unroll
    for (int nt = 0; nt < 4; ++nt) {
      float s = acc2[nt][0] + acc2[nt][1] + acc2[nt][2] + acc2[nt][3] + 4.0f * b2v[nt];
      s += __shfl_xor(s, 16, 64);
      s += __shfl_xor(s, 32, 64);
      if (q == 0)
        unsafeAtomicAdd(&sums[(size_t)guni * MDIM + nt * 16 + r15], s);
    }
  } else {
    int nb = stripbase + q * 4;
    int gv[4];
    #pragma unroll
    for (int r = 0; r < 4; ++r) gv[r] = (nb + r < N) ? batch[nb + r] : -1;
    #pragma unroll
    for (int nt = 0; nt < 4; ++nt) {
      float run = 0.f;
      #pragma unroll
      for (int r = 0; r < 4; ++r) {
        bool valid = gv[r] >= 0;
        run += valid ? (acc2[nt][r] + b2v[nt]) : 0.f;
        bool endrun = valid && ((r == 3) ? true : (gv[r + 1] != gv[r]));
        if (endrun) {
          unsafeAtomicAdd(&sums[(size_t)gv[r] * MDIM + nt * 16 + r15], run);
          run = 0.f;
        }
      }
    }
  }
}

// ============ final: out = sums / counts ============
__global__ __launch_bounds__(256) void final_div_k(const float* __restrict__ sums,
                                                   const int* __restrict__ batch,
                                                   float* __restrict__ out, int N) {
  int i = blockIdx.x * 256 + threadIdx.x;
  if (i >= GNUM * MDIM) return;
  int g = i >> 6;
  int lo = 0, hi = N;
  while (lo < hi) { int mid = (lo + hi) >> 1; if (batch[mid] < g) lo = mid + 1; else hi = mid; }
  int lb = lo;
  lo = 0; hi = N;
  while (lo < hi) { int mid = (lo + hi) >> 1; if (batch[mid] < g + 1) lo = mid + 1; else hi = mid; }
  float cnt = (float)(lo - lb);
  out[i] = sums[i] / fmaxf(cnt, 1.0f);
}

extern "C" void kernel_launch(void* const* d_in, const int* in_sizes, int n_in,
                              void* d_out, int out_size, void* d_ws, size_t ws_size,
                              hipStream_t stream) {
  const float* x   = (const float*)d_in[0];
  const int* ei    = (const int*)d_in[1];
  const int* batch = (const int*)d_in[2];
  const float* W1  = (const float*)d_in[3];
  const float* b1  = (const float*)d_in[4];
  const float* W2  = (const float*)d_in[5];
  const float* b2  = (const float*)d_in[6];
  float* out = (float*)d_out;

  const int N = in_sizes[0] / HDIM;   // 100000
  const int E = in_sizes[1] / 2;      // 400000
  const int NB = (N + 1023) / 1024;

  int* degInt   = (int*)d_ws;                        // N
  float* sums   = (float*)(degInt + N);              // 8192
  u16* x_bf     = (u16*)(sums + GNUM * MDIM);        // N*256
  u16* agg_bf   = x_bf + (size_t)N * HDIM;           // N*256
  int* nodeOff  = (int*)(agg_bf + (size_t)N * HDIM); // N
  int* cursor   = nodeOff + N;                       // N
  int* blkSum   = cursor + N;                        // 128
  int* blkOff   = blkSum + 128;                      // 128
  int* csrDst   = blkOff + 128;                      // E
  u16* W1Fh     = (u16*)(csrDst + E);                // 384*512
  u16* W1Fl     = W1Fh + 196608;
  u16* W2Fh     = W1Fl + 196608;                     // 32*512
  u16* W2Fl     = W2Fh + 16384;

  hipMemsetAsync(d_ws, 0, (size_t)(N + GNUM * MDIM) * sizeof(int), stream);

  prep_k<<<104, 256, 0, stream>>>(W1, W2, W1Fh, W1Fl, W2Fh, W2Fl);
  cvt_k<<<(N * 32 + 255) / 256, 256, 0, stream>>>(x, x_bf, N * 32);
  count_k<<<(E + 255) / 256, 256, 0, stream>>>(ei, degInt, E);
  scan1_k<<<NB, 256, 0, stream>>>(degInt, nodeOff, blkSum, N);
  scan2_k<<<1, 128, 0, stream>>>(blkSum, blkOff, NB);
  scan3_k<<<(N + 255) / 256, 256, 0, stream>>>(nodeOff, blkOff, cursor, N);
  fill_k<<<(E + 255) / 256, 256, 0, stream>>>(ei, cursor, csrDst, E);
  agg_k<<<(N + 3) / 4, 256, 0, stream>>>(x_bf, nodeOff, degInt, csrDst, agg_bf, N);
  fused_mfma_k<<<(N + 63) / 64, 256, 0, stream>>>(x_bf, agg_bf, batch, W1Fh, W1Fl, b1,
                                                  W2Fh, W2Fl, b2, sums, N);
  final_div_k<<<(GNUM * MDIM + 255) / 256, 256, 0, stream>>>(sums, batch, out, N);
}

// Round 8
// 401.316 us; speedup vs baseline: 1.1596x; 1.0464x over previous
//
#include <hip/hip_runtime.h>

#define HDIM 256
#define MDIM 64
#define GNUM 128

typedef short bf16x8 __attribute__((ext_vector_type(8)));
typedef float f32x4 __attribute__((ext_vector_type(4)));
typedef unsigned short u16;
typedef unsigned int u32;

__device__ __forceinline__ u32 f2bf(float f) {
  u32 u = __float_as_uint(f);
  return (u + 0x7FFFu + ((u >> 16) & 1u)) >> 16;   // RNE
}
__device__ __forceinline__ float bf2f(u16 h) {
  return __uint_as_float((u32)h << 16);
}
__device__ __forceinline__ u32 pack2(float a, float b) {
  return f2bf(a) | (f2bf(b) << 16);
}
__device__ __forceinline__ bf16x8 bfmul8(bf16x8 a, bf16x8 b) {
  bf16x8 r;
  #pragma unroll
  for (int i = 0; i < 8; i += 2) {
    float x0 = bf2f((u16)a[i]),     y0 = bf2f((u16)b[i]);
    float x1 = bf2f((u16)a[i + 1]), y1 = bf2f((u16)b[i + 1]);
    u32 p = pack2(x0 * y0, x1 * y1);
    r[i] = (short)(p & 0xffff);
    r[i + 1] = (short)(p >> 16);
  }
  return r;
}
__device__ __forceinline__ void gload_lds16(const void* g, void* l) {
  __builtin_amdgcn_global_load_lds(
      (const __attribute__((address_space(1))) u32*)g,
      (__attribute__((address_space(3))) u32*)l, 16, 0, 0);
}

// ============ stage1: prep W frags | cvt x->swizzled bf16 | count degrees ============
// blocks [0,104): W1F/W2F hi-lo fragment-major prep (layout as R7).
// blocks [104,104+cvtB): x f32 -> x_bf, rows 512 B, 16-B granule g stored at g^(node&7).
// blocks [104+cvtB, ...): degree count.
__global__ __launch_bounds__(256) void stage1_k(
    const float* __restrict__ x, const float* __restrict__ W1,
    const float* __restrict__ W2, const int* __restrict__ ei,
    int* __restrict__ degInt, u16* __restrict__ x_bf,
    u16* __restrict__ W1Fh, u16* __restrict__ W1Fl,
    u16* __restrict__ W2Fh, u16* __restrict__ W2Fl,
    int N, int E, int cvtB) {
  int b = blockIdx.x, t = threadIdx.x;
  if (b < 104) {
    int tid = b * 256 + t;
    if (tid < 24576) {
      int rec = tid >> 6, l = tid & 63;
      int c = rec >> 5, rem = rec & 31;
      int ks = rem >> 4, w = (rem >> 2) & 3, ht = rem & 3;
      int q = l >> 4, r = l & 15;
      int hcol = w * 64 + ht * 16 + r;
      int kg0 = (c % 3) * 256 + (c / 3) * 64 + ks * 32 + q * 8;
      #pragma unroll
      for (int i = 0; i < 8; ++i) {
        float f = W1[(size_t)(kg0 + i) * HDIM + hcol];
        u16 h = (u16)f2bf(f);
        W1Fh[tid * 8 + i] = h;
        W1Fl[tid * 8 + i] = (u16)f2bf(f - bf2f(h));
      }
    } else if (tid < 24576 + 2048) {
      int t2 = tid - 24576;
      int rec = t2 >> 6, l = t2 & 63;
      int ks2 = rec >> 2, nt = rec & 3;
      int q = l >> 4, r = l & 15;
      int m = nt * 16 + r;
      int k0 = ks2 * 32 + q * 8;
      #pragma unroll
      for (int i = 0; i < 8; ++i) {
        float f = W2[(size_t)(k0 + i) * MDIM + m];
        u16 h = (u16)f2bf(f);
        W2Fh[t2 * 8 + i] = h;
        W2Fl[t2 * 8 + i] = (u16)f2bf(f - bf2f(h));
      }
    }
  } else if (b < 104 + cvtB) {
    int gidx = (b - 104) * 256 + t;          // granule index
    if (gidx < N * 32) {
      int node = gidx >> 5, g = gidx & 31;
      const float4* p = (const float4*)(x + (size_t)node * HDIM + g * 8);
      float4 a = p[0], b4 = p[1];
      uint4 o = make_uint4(pack2(a.x, a.y), pack2(a.z, a.w),
                           pack2(b4.x, b4.y), pack2(b4.z, b4.w));
      *(uint4*)((char*)x_bf + (size_t)node * 512 + ((g ^ (node & 7)) << 4)) = o;
    }
  } else {
    int e = (b - 104 - cvtB) * 256 + t;
    if (e < E) atomicAdd(&degInt[ei[e]], 1);
  }
}

// ============ scans + fill (CSR) ============
__global__ __launch_bounds__(256) void scan1_k(const int* __restrict__ degInt,
                                               int* __restrict__ nodeOff,
                                               int* __restrict__ blkSum, int N) {
  __shared__ int sdata[256];
  int b = blockIdx.x, t = threadIdx.x;
  int base = b * 1024 + t * 4;
  int v[4];
  #pragma unroll
  for (int q = 0; q < 4; ++q) v[q] = (base + q < N) ? degInt[base + q] : 0;
  int tsum = v[0] + v[1] + v[2] + v[3];
  sdata[t] = tsum;
  __syncthreads();
  for (int off = 1; off < 256; off <<= 1) {
    int xv = (t >= off) ? sdata[t - off] : 0;
    __syncthreads();
    sdata[t] += xv;
    __syncthreads();
  }
  int run = sdata[t] - tsum;
  #pragma unroll
  for (int q = 0; q < 4; ++q) {
    if (base + q < N) nodeOff[base + q] = run;
    run += v[q];
  }
  if (t == 255) blkSum[b] = sdata[255];
}

__global__ __launch_bounds__(128) void scan2_k(const int* __restrict__ blkSum,
                                               int* __restrict__ blkOff, int NB) {
  __shared__ int sdata[128];
  int t = threadIdx.x;
  int v = (t < NB) ? blkSum[t] : 0;
  sdata[t] = v;
  __syncthreads();
  for (int off = 1; off < 128; off <<= 1) {
    int xv = (t >= off) ? sdata[t - off] : 0;
    __syncthreads();
    sdata[t] += xv;
    __syncthreads();
  }
  if (t < NB) blkOff[t] = sdata[t] - v;
}

__global__ __launch_bounds__(256) void scan3_k(int* __restrict__ nodeOff,
                                               const int* __restrict__ blkOff,
                                               int* __restrict__ cursor, int N) {
  int i = blockIdx.x * 256 + threadIdx.x;
  if (i >= N) return;
  int off = nodeOff[i] + blkOff[i >> 10];
  nodeOff[i] = off;
  cursor[i] = off;
}

__global__ __launch_bounds__(256) void fill_k(const int* __restrict__ ei,
                                              int* __restrict__ cursor,
                                              int* __restrict__ csrDst, int E) {
  int e = blockIdx.x * 256 + threadIdx.x;
  if (e >= E) return;
  int p = atomicAdd(&cursor[ei[e]], 1);
  csrDst[p] = ei[E + e];
}

// ============ fused: stage x-panel + gather-agg -> LDS; GEMM1; GEMM2; pool ============
// 64 nodes/block, 4 waves. LDS: x-panel [0,32K) (gload_lds of pre-swizzled x_bf),
// agg-panel [32K,64K) (in-kernel CSR gather). GEMM1 A-frags from LDS; W from L2
// fragment-major ping-pong. Hs aliases x-panel after barrier.
__global__ __launch_bounds__(256, 2) void fused_mfma_k(
    const u16* __restrict__ x_bf, const int* __restrict__ batch,
    const u16* __restrict__ W1Fh, const u16* __restrict__ W1Fl,
    const float* __restrict__ b1,
    const u16* __restrict__ W2Fh, const u16* __restrict__ W2Fl,
    const float* __restrict__ b2,
    const int* __restrict__ nodeOff, const int* __restrict__ degInt,
    const int* __restrict__ csrDst,
    float* __restrict__ sums, int N) {
  __shared__ __align__(16) char smem[65536];

  const int t = threadIdx.x;
  const int w = t >> 6;
  const int l = t & 63;
  const int r15 = l & 15;
  const int q = l >> 4;
  const int n0 = blockIdx.x * 64;
  const char* xB = (const char*)x_bf;

  // ---- stage x-panel (swizzled rows, linear copy) ----
  #pragma unroll
  for (int i = 0; i < 8; ++i) {
    int off = t * 16 + i * 4096;
    gload_lds16(xB + (size_t)n0 * 512 + off, smem + off);
  }

  // ---- gather agg for this wave's 16 nodes -> agg panel ----
  {
    const int wb = w * 16;
    const int lxor = l * 8;
    for (int i = 0; i < 16; ++i) {
      int nodeLocal = wb + i;
      int gnode = n0 + nodeLocal;
      float a0 = 0.f, a1 = 0.f, a2 = 0.f, a3 = 0.f;
      if (gnode < N) {
        int deg = degInt[gnode];
        int start = nodeOff[gnode];
#define ADDV(v)                          \
        a0 += bf2f((u16)((v).x & 0xffff)); \
        a1 += bf2f((u16)((v).x >> 16));    \
        a2 += bf2f((u16)((v).y & 0xffff)); \
        a3 += bf2f((u16)((v).y >> 16));
        int j = 0;
        for (; j + 4 <= deg; j += 4) {
          int d0 = csrDst[start + j + 0];
          int d1 = csrDst[start + j + 1];
          int d2 = csrDst[start + j + 2];
          int d3 = csrDst[start + j + 3];
          uint2 v0 = *(const uint2*)(xB + (size_t)d0 * 512 + (lxor ^ ((d0 & 7) << 4)));
          uint2 v1 = *(const uint2*)(xB + (size_t)d1 * 512 + (lxor ^ ((d1 & 7) << 4)));
          uint2 v2 = *(const uint2*)(xB + (size_t)d2 * 512 + (lxor ^ ((d2 & 7) << 4)));
          uint2 v3 = *(const uint2*)(xB + (size_t)d3 * 512 + (lxor ^ ((d3 & 7) << 4)));
          ADDV(v0) ADDV(v1) ADDV(v2) ADDV(v3)
        }
        for (; j < deg; ++j) {
          int d = csrDst[start + j];
          uint2 v = *(const uint2*)(xB + (size_t)d * 512 + (lxor ^ ((d & 7) << 4)));
          ADDV(v)
        }
#undef ADDV
        float s = deg > 0 ? 1.0f / (float)deg : 0.0f;
        a0 *= s; a1 *= s; a2 *= s; a3 *= s;
      }
      *(uint2*)(smem + 32768 + nodeLocal * 512 + (lxor ^ ((nodeLocal & 7) << 4))) =
          make_uint2(pack2(a0, a1), pack2(a2, a3));
    }
  }
  __syncthreads();   // x-panel staged (vmcnt) + agg written (lgkm)

  // ---- GEMM1: 12 chunks x 2 k-steps; A from LDS, W ping-pong from L2 ----
  f32x4 acc[4][4];
  #pragma unroll
  for (int i = 0; i < 4; ++i)
    #pragma unroll
    for (int j = 0; j < 4; ++j) acc[i][j] = (f32x4){0.f, 0.f, 0.f, 0.f};

  bf16x8 W0h[4], W0l[4], W1h_[4], W1l_[4];

#define LOADW(s, WH, WL)                                                        \
  {                                                                             \
    _Pragma("unroll")                                                           \
    for (int ht = 0; ht < 4; ++ht) {                                            \
      size_t off = (size_t)(s)*16384 + (size_t)w * 4096 + (size_t)ht * 1024 +   \
                   (size_t)l * 16;                                              \
      WH[ht] = *(const bf16x8*)((const char*)W1Fh + off);                       \
      WL[ht] = *(const bf16x8*)((const char*)W1Fl + off);                       \
    }                                                                           \
  }
#define CONSL(s, WH, WL)                                                        \
  {                                                                             \
    const int c_ = (s) >> 1, seg_ = c_ % 3, qk_ = c_ / 3, ks_ = (s)&1;          \
    bf16x8 bfr[4];                                                              \
    _Pragma("unroll")                                                           \
    for (int nt = 0; nt < 4; ++nt) {                                            \
      int row = nt * 16 + r15;                                                  \
      int coff = ((qk_ * 8 + ks_ * 4 + q) ^ (row & 7)) << 4;                    \
      if (seg_ == 0) {                                                          \
        bfr[nt] = *(const bf16x8*)(smem + row * 512 + coff);                    \
      } else if (seg_ == 1) {                                                   \
        bfr[nt] = *(const bf16x8*)(smem + 32768 + row * 512 + coff);            \
      } else {                                                                  \
        bf16x8 xv = *(const bf16x8*)(smem + row * 512 + coff);                  \
        bf16x8 av = *(const bf16x8*)(smem + 32768 + row * 512 + coff);          \
        bfr[nt] = bfmul8(xv, av);                                               \
      }                                                                         \
    }                                                                           \
    __builtin_amdgcn_s_setprio(1);                                              \
    _Pragma("unroll")                                                           \
    for (int ht = 0; ht < 4; ++ht) {                                            \
      _Pragma("unroll")                                                         \
      for (int nt = 0; nt < 4; ++nt)                                            \
        acc[ht][nt] = __builtin_amdgcn_mfma_f32_16x16x32_bf16(WH[ht], bfr[nt],  \
                                                              acc[ht][nt], 0, 0, 0); \
      _Pragma("unroll")                                                         \
      for (int nt = 0; nt < 4; ++nt)                                            \
        acc[ht][nt] = __builtin_amdgcn_mfma_f32_16x16x32_bf16(WL[ht], bfr[nt],  \
                                                              acc[ht][nt], 0, 0, 0); \
    }                                                                           \
    __builtin_amdgcn_s_setprio(0);                                              \
  }

  LOADW(0, W0h, W0l)
  #pragma unroll
  for (int c = 0; c < 12; ++c) {
    const int s0 = 2 * c;
    LOADW(s0 + 1, W1h_, W1l_)
    CONSL(s0, W0h, W0l)
    if (c < 11) {
      LOADW(s0 + 2, W0h, W0l)
    }
    CONSL(s0 + 1, W1h_, W1l_)
  }
#undef LOADW
#undef CONSL

  __syncthreads();   // all A-reads done before Hs overwrites x-panel

  // ---- h = relu(acc + b1) -> Hs bf16 (aliases x-panel) ----
  #pragma unroll
  for (int mt = 0; mt < 4; ++mt) {
    float4 b1v = *(const float4*)(b1 + w * 64 + mt * 16 + q * 4);
    #pragma unroll
    for (int nt = 0; nt < 4; ++nt) {
      f32x4 a = acc[mt][nt];
      float h0 = fmaxf(a[0] + b1v.x, 0.f);
      float h1 = fmaxf(a[1] + b1v.y, 0.f);
      float h2 = fmaxf(a[2] + b1v.z, 0.f);
      float h3 = fmaxf(a[3] + b1v.w, 0.f);
      int node = nt * 16 + r15;
      int hcol = w * 64 + mt * 16 + q * 4;
      int byte = (node * 512 + hcol * 2) ^ ((r15 & 7) << 4);
      *(uint2*)(smem + byte) = make_uint2(pack2(h0, h1), pack2(h2, h3));
    }
  }
  __syncthreads();

  // ---- GEMM2: wave w -> nodes [16w,16w+16); W2 frags from global ----
  f32x4 acc2[4];
  #pragma unroll
  for (int nt = 0; nt < 4; ++nt) acc2[nt] = (f32x4){0.f, 0.f, 0.f, 0.f};
  #pragma unroll
  for (int ks2 = 0; ks2 < 8; ++ks2) {
    int hb = ((w * 16 + r15) * 512 + ks2 * 64 + q * 16) ^ ((r15 & 7) << 4);
    bf16x8 ah = *(const bf16x8*)(smem + hb);
    #pragma unroll
    for (int nt = 0; nt < 4; ++nt) {
      int rec2 = ks2 * 4 + nt;
      bf16x8 wbh = *(const bf16x8*)(W2Fh + rec2 * 512 + l * 8);
      bf16x8 wbl = *(const bf16x8*)(W2Fl + rec2 * 512 + l * 8);
      acc2[nt] = __builtin_amdgcn_mfma_f32_16x16x32_bf16(ah, wbh, acc2[nt], 0, 0, 0);
      acc2[nt] = __builtin_amdgcn_mfma_f32_16x16x32_bf16(ah, wbl, acc2[nt], 0, 0, 0);
    }
  }

  // ---- pool ----
  float b2v[4];
  #pragma unroll
  for (int nt = 0; nt < 4; ++nt) b2v[nt] = b2[nt * 16 + r15];

  int stripbase = n0 + w * 16;
  int guni = -1;
  if (stripbase + 15 < N) {
    int gf = batch[stripbase], gl = batch[stripbase + 15];
    if (gf == gl) guni = gf;
  }
  if (guni >= 0) {
    #pragma unroll
    for (int nt = 0; nt < 4; ++nt) {
      float s = acc2[nt][0] + acc2[nt][1] + acc2[nt][2] + acc2[nt][3] + 4.0f * b2v[nt];
      s += __shfl_xor(s, 16, 64);
      s += __shfl_xor(s, 32, 64);
      if (q == 0)
        unsafeAtomicAdd(&sums[(size_t)guni * MDIM + nt * 16 + r15], s);
    }
  } else {
    int nb = stripbase + q * 4;
    int gv[4];
    #pragma unroll
    for (int r = 0; r < 4; ++r) gv[r] = (nb + r < N) ? batch[nb + r] : -1;
    #pragma unroll
    for (int nt = 0; nt < 4; ++nt) {
      float run = 0.f;
      #pragma unroll
      for (int r = 0; r < 4; ++r) {
        bool valid = gv[r] >= 0;
        run += valid ? (acc2[nt][r] + b2v[nt]) : 0.f;
        bool endrun = valid && ((r == 3) ? true : (gv[r + 1] != gv[r]));
        if (endrun) {
          unsafeAtomicAdd(&sums[(size_t)gv[r] * MDIM + nt * 16 + r15], run);
          run = 0.f;
        }
      }
    }
  }
}

// ============ final: out = sums / counts ============
__global__ __launch_bounds__(256) void final_div_k(const float* __restrict__ sums,
                                                   const int* __restrict__ batch,
                                                   float* __restrict__ out, int N) {
  int i = blockIdx.x * 256 + threadIdx.x;
  if (i >= GNUM * MDIM) return;
  int g = i >> 6;
  int lo = 0, hi = N;
  while (lo < hi) { int mid = (lo + hi) >> 1; if (batch[mid] < g) lo = mid + 1; else hi = mid; }
  int lb = lo;
  lo = 0; hi = N;
  while (lo < hi) { int mid = (lo + hi) >> 1; if (batch[mid] < g + 1) lo = mid + 1; else hi = mid; }
  float cnt = (float)(lo - lb);
  out[i] = sums[i] / fmaxf(cnt, 1.0f);
}

extern "C" void kernel_launch(void* const* d_in, const int* in_sizes, int n_in,
                              void* d_out, int out_size, void* d_ws, size_t ws_size,
                              hipStream_t stream) {
  const float* x   = (const float*)d_in[0];
  const int* ei    = (const int*)d_in[1];
  const int* batch = (const int*)d_in[2];
  const float* W1  = (const float*)d_in[3];
  const float* b1  = (const float*)d_in[4];
  const float* W2  = (const float*)d_in[5];
  const float* b2  = (const float*)d_in[6];
  float* out = (float*)d_out;

  const int N = in_sizes[0] / HDIM;   // 100000
  const int E = in_sizes[1] / 2;      // 400000
  const int NB = (N + 1023) / 1024;
  const int cvtB = (N * 32 + 255) / 256;
  const int cntB = (E + 255) / 256;

  int* degInt   = (int*)d_ws;                        // N
  float* sums   = (float*)(degInt + N);              // 8192
  u16* x_bf     = (u16*)(sums + GNUM * MDIM);        // N*256 (rows pre-swizzled)
  int* nodeOff  = (int*)(x_bf + (size_t)N * HDIM);   // N
  int* cursor   = nodeOff + N;                       // N
  int* blkSum   = cursor + N;                        // 128
  int* blkOff   = blkSum + 128;                      // 128
  int* csrDst   = blkOff + 128;                      // E
  u16* W1Fh     = (u16*)(csrDst + E);                // 384*512
  u16* W1Fl     = W1Fh + 196608;
  u16* W2Fh     = W1Fl + 196608;                     // 32*512
  u16* W2Fl     = W2Fh + 16384;

  hipMemsetAsync(d_ws, 0, (size_t)(N + GNUM * MDIM) * sizeof(int), stream);

  stage1_k<<<104 + cvtB + cntB, 256, 0, stream>>>(x, W1, W2, ei, degInt, x_bf,
                                                  W1Fh, W1Fl, W2Fh, W2Fl, N, E, cvtB);
  scan1_k<<<NB, 256, 0, stream>>>(degInt, nodeOff, blkSum, N);
  scan2_k<<<1, 128, 0, stream>>>(blkSum, blkOff, NB);
  scan3_k<<<(N + 255) / 256, 256, 0, stream>>>(nodeOff, blkOff, cursor, N);
  fill_k<<<(E + 255) / 256, 256, 0, stream>>>(ei, cursor, csrDst, E);
  fused_mfma_k<<<(N + 63) / 64, 256, 0, stream>>>(x_bf, batch, W1Fh, W1Fl, b1,
                                                  W2Fh, W2Fl, b2, nodeOff, degInt,
                                                  csrDst, sums, N);
  final_div_k<<<(GNUM * MDIM + 255) / 256, 256, 0, stream>>>(sums, batch, out, N);
}